// Round 1
// baseline (125.265 us; speedup 1.0000x reference)
//
#include <hip/hip_runtime.h>
#include <hip/hip_bf16.h>

// Problem constants (from reference):
#define B 4
#define N 256
#define F 128
#define H 256
// OUT = 1

// ---------------------------------------------------------------------------
// k1: per batch: x_mean = mean_i x[b,i,:]; h_pooled = relu(x_mean @ W_pool);
//     ub[b,h] = b1[h] + sum_f h_pooled[f] * W1[f,h]   (the "pooled" third of W1)
// grid = B, block = 256
// ---------------------------------------------------------------------------
__global__ __launch_bounds__(256) void k1_pooled(
    const float* __restrict__ x, const float* __restrict__ Wp,
    const float* __restrict__ W1, const float* __restrict__ b1,
    float* __restrict__ ub) {
  __shared__ float part[256];
  __shared__ float xm[F];
  __shared__ float rp[F];
  const int b = blockIdx.x;
  const int t = threadIdx.x;
  const int f = t & (F - 1);
  const int half = t >> 7;  // 0 or 1
  const float* xb = x + (size_t)b * N * F;

  // partial sums over nodes: half 0 sums rows 0..127, half 1 sums 128..255
  float s = 0.f;
  const int i0 = half * 128;
  for (int i = i0; i < i0 + 128; ++i) s += xb[(size_t)i * F + f];
  part[t] = s;
  __syncthreads();
  if (t < F) xm[t] = (part[t] + part[t + 128]) * (1.f / (float)N);
  __syncthreads();
  // h_pooled = relu(xm @ Wp), Wp is [F,F] row-major [in,out]
  if (t < F) {
    float acc = 0.f;
    for (int k = 0; k < F; ++k) acc = fmaf(xm[k], Wp[k * F + t], acc);
    rp[t] = fmaxf(acc, 0.f);
  }
  __syncthreads();
  // ub[b,h] = b1[h] + rp @ W1[0:F, :]
  float acc = b1[t];
  for (int k = 0; k < F; ++k) acc = fmaf(rp[k], W1[k * H + t], acc);
  ub[b * H + t] = acc;
}

// ---------------------------------------------------------------------------
// k2: A[b,i,h] = ub[b,h] + relu(x[b,i,:]) @ W1[F:2F, :]
//     W[b,j,h] =           relu(x[b,j,:]) @ W1[2F:3F, :]
// 4 rows per block to reuse the coalesced W1 row reads.
// grid = B*N/4 = 256, block = 256 (thread = h)
// ---------------------------------------------------------------------------
__global__ __launch_bounds__(256) void k2_rows(
    const float* __restrict__ x, const float* __restrict__ W1,
    const float* __restrict__ ub, float* __restrict__ A,
    float* __restrict__ W) {
  __shared__ float xr[4][F];
  const int blk = blockIdx.x;
  const int b = blk >> 6;           // 64 row-groups per batch
  const int i0 = (blk & 63) * 4;
  const int t = threadIdx.x;        // h

  // stage 4 relu'd input rows (4*128 = 512 floats)
  for (int idx = t; idx < 4 * F; idx += 256) {
    int r = idx >> 7, f = idx & (F - 1);
    xr[r][f] = fmaxf(x[((size_t)(b * N + i0 + r)) * F + f], 0.f);
  }
  __syncthreads();

  float aA[4], aW[4];
  const float u = ub[b * H + t];
#pragma unroll
  for (int r = 0; r < 4; ++r) { aA[r] = u; aW[r] = 0.f; }

  const float* W1i = W1 + (size_t)F * H;      // rows F..2F-1
  const float* W1j = W1 + (size_t)(2 * F) * H;// rows 2F..3F-1
  for (int f = 0; f < F; ++f) {
    const float wi = W1i[f * H + t];
    const float wj = W1j[f * H + t];
#pragma unroll
    for (int r = 0; r < 4; ++r) {
      const float xv = xr[r][f];   // LDS broadcast
      aA[r] = fmaf(xv, wi, aA[r]);
      aW[r] = fmaf(xv, wj, aW[r]);
    }
  }
#pragma unroll
  for (int r = 0; r < 4; ++r) {
    A[((size_t)(b * N + i0 + r)) * H + t] = aA[r];
    W[((size_t)(b * N + i0 + r)) * H + t] = aW[r];
  }
}

// ---------------------------------------------------------------------------
// k3: out[b,i,j] = b2 + sum_h relu(A[b,i,h] + W[b,j,h]) * W2[h]
// 32x32 output tile per block, 2x2 per thread, h-major (transposed) LDS with
// stride 34 (even pad -> 8B-aligned float2, conflict-free: a reads are
// 16-way broadcasts, w reads span all 32 banks with 4-way broadcast).
// h processed in 2 chunks of 128 to keep LDS at ~36 KB.
// grid = (N/32, N/32, B) = (8,8,4), block = 256
// ---------------------------------------------------------------------------
#define K3_STRIDE 34
__global__ __launch_bounds__(256) void k3_pairwise(
    const float* __restrict__ A, const float* __restrict__ W,
    const float* __restrict__ W2, const float* __restrict__ b2,
    float* __restrict__ out) {
  __shared__ float aT[128 * K3_STRIDE];  // [h_local][row 0..31]
  __shared__ float wT[128 * K3_STRIDE];
  __shared__ float w2s[H];

  const int b = blockIdx.z;
  const int i0 = blockIdx.y * 32;
  const int j0 = blockIdx.x * 32;
  const int t = threadIdx.x;
  const int tj = t & 15;
  const int ti = t >> 4;

  const float* Ab = A + ((size_t)(b * N + i0)) * H;
  const float* Wb = W + ((size_t)(b * N + j0)) * H;

  w2s[t] = W2[t];

  float acc00 = 0.f, acc01 = 0.f, acc10 = 0.f, acc11 = 0.f;

  const int hh = t & 127;   // h within chunk (coalesced global reads)
  const int rh = t >> 7;    // 0/1 -> which 16 rows to stage

  for (int c = 0; c < 2; ++c) {
    const int hbase = c * 128;
    // stage 32 rows x 128 h (transposed) : 16 elements per thread per array
#pragma unroll
    for (int k = 0; k < 16; ++k) {
      const int r = rh * 16 + k;
      aT[hh * K3_STRIDE + r] = Ab[(size_t)r * H + hbase + hh];
      wT[hh * K3_STRIDE + r] = Wb[(size_t)r * H + hbase + hh];
    }
    __syncthreads();

    const float* w2c = w2s + hbase;
    for (int h = 0; h < 128; ++h) {
      const float2 av = *(const float2*)(aT + h * K3_STRIDE + 2 * ti);
      const float2 wv = *(const float2*)(wT + h * K3_STRIDE + 2 * tj);
      const float w2h = w2c[h];
      acc00 = fmaf(fmaxf(av.x + wv.x, 0.f), w2h, acc00);
      acc01 = fmaf(fmaxf(av.x + wv.y, 0.f), w2h, acc01);
      acc10 = fmaf(fmaxf(av.y + wv.x, 0.f), w2h, acc10);
      acc11 = fmaf(fmaxf(av.y + wv.y, 0.f), w2h, acc11);
    }
    __syncthreads();
  }

  const float bb = b2[0];
  const int i = i0 + 2 * ti;
  const int j = j0 + 2 * tj;
  float* o0 = out + ((size_t)(b * N + i)) * N + j;
  float* o1 = out + ((size_t)(b * N + i + 1)) * N + j;
  o0[0] = acc00 + bb;
  o0[1] = acc01 + bb;
  o1[0] = acc10 + bb;
  o1[1] = acc11 + bb;
}

extern "C" void kernel_launch(void* const* d_in, const int* in_sizes, int n_in,
                              void* d_out, int out_size, void* d_ws, size_t ws_size,
                              hipStream_t stream) {
  const float* x  = (const float*)d_in[0];  // [B,N,F]
  const float* Wp = (const float*)d_in[1];  // [F,F]
  const float* W1 = (const float*)d_in[2];  // [3F,H]
  const float* b1 = (const float*)d_in[3];  // [H]
  const float* W2 = (const float*)d_in[4];  // [H,1]
  const float* b2 = (const float*)d_in[5];  // [1]
  float* out = (float*)d_out;               // [B,N,N,1]

  float* ws = (float*)d_ws;
  float* ub = ws;                           // B*H          = 1024
  float* A  = ws + B * H;                   // B*N*H        = 262144
  float* Wt = ws + B * H + B * N * H;       // B*N*H        = 262144
  // total: 525312 floats = 2.1 MB of d_ws

  k1_pooled<<<dim3(B), dim3(256), 0, stream>>>(x, Wp, W1, b1, ub);
  k2_rows<<<dim3(B * N / 4), dim3(256), 0, stream>>>(x, W1, ub, A, Wt);
  k3_pairwise<<<dim3(N / 32, N / 32, B), dim3(256), 0, stream>>>(A, Wt, W2, b2, out);
}

// Round 2
// 99.344 us; speedup vs baseline: 1.2609x; 1.2609x over previous
//
#include <hip/hip_runtime.h>
#include <hip/hip_bf16.h>

// Problem constants (from reference):
#define B 4
#define N 256
#define F 128
#define H 256
// OUT = 1

// ---------------------------------------------------------------------------
// k1a: column sums of x per batch -> atomicAdd into xm_acc[b*F+f] (pre-zeroed)
// grid = B*16 = 64 blocks, block = 256. Each block: 16 rows (8 KB), float4.
// ---------------------------------------------------------------------------
__global__ __launch_bounds__(256) void k1a_mean(const float* __restrict__ x,
                                                float* __restrict__ xm_acc) {
  __shared__ float4 red[256];
  const int b = blockIdx.x >> 4;
  const int rg = blockIdx.x & 15;
  const int t = threadIdx.x;
  // 16 rows * 128 cols = 512 float4; thread t takes float4 #t and #(t+256);
  // both have the same column group c = t & 31 (256 % 32 == 0).
  const float4* xb4 = (const float4*)(x + (b * N + rg * 16) * F);
  float4 a = xb4[t];
  float4 c4 = xb4[t + 256];
  float4 s;
  s.x = a.x + c4.x; s.y = a.y + c4.y; s.z = a.z + c4.z; s.w = a.w + c4.w;
  red[t] = s;
  __syncthreads();
  if (t < 32) {
    float4 acc = red[t];
#pragma unroll
    for (int m = 1; m < 8; ++m) {
      float4 v = red[t + 32 * m];
      acc.x += v.x; acc.y += v.y; acc.z += v.z; acc.w += v.w;
    }
    float* dst = xm_acc + b * F + 4 * t;
    atomicAdd(dst + 0, acc.x);
    atomicAdd(dst + 1, acc.y);
    atomicAdd(dst + 2, acc.z);
    atomicAdd(dst + 3, acc.w);
  }
}

// ---------------------------------------------------------------------------
// k1b: rp = relu((xm/N) @ Wp);  ub[b, hrange] = b1 + rp @ W1[0:F, hrange]
// grid = B*2 (b, q = h-half), block = 256; 2 threads per output, 64 MACs each.
// ---------------------------------------------------------------------------
__global__ __launch_bounds__(256) void k1b_pooled(
    const float* __restrict__ xm_acc, const float* __restrict__ Wp,
    const float* __restrict__ W1, const float* __restrict__ b1,
    float* __restrict__ ub) {
  __shared__ float xm_s[F];
  __shared__ float rp_s[F];
  __shared__ float part[256];
  const int b = blockIdx.x >> 1;
  const int q = blockIdx.x & 1;
  const int t = threadIdx.x;
  const int lo = t & 127;   // output index within 128
  const int kh = t >> 7;    // which k-half this thread sums

  if (t < F) xm_s[t] = xm_acc[b * F + t] * (1.f / (float)N);
  __syncthreads();

  // rp[f] = relu(sum_k xm[k] * Wp[k*F + f])
  {
    float acc = 0.f;
    const int k0 = kh * 64;
#pragma unroll 8
    for (int kk = 0; kk < 64; ++kk) {
      const int k = k0 + kk;
      acc = fmaf(xm_s[k], Wp[k * F + lo], acc);
    }
    part[t] = acc;
  }
  __syncthreads();
  if (t < F) rp_s[t] = fmaxf(part[t] + part[t + 128], 0.f);
  __syncthreads();

  // ub[b, q*128 + lo] = b1[..] + sum_k rp[k] * W1[k*H + h]
  {
    const int h = q * 128 + lo;
    float acc = 0.f;
    const int k0 = kh * 64;
#pragma unroll 8
    for (int kk = 0; kk < 64; ++kk) {
      const int k = k0 + kk;
      acc = fmaf(rp_s[k], W1[k * H + h], acc);
    }
    part[t] = acc;
  }
  __syncthreads();
  if (t < F) {
    const int h = q * 128 + t;
    ub[b * H + h] = part[t] + part[t + 128] + b1[h];
  }
}

// ---------------------------------------------------------------------------
// k2: A[b,i,h] = ub[b,h] + relu(x[b,i,:]) @ W1[F:2F, :]
//     W[b,j,h] =           relu(x[b,j,:]) @ W1[2F:3F, :]
// grid = B*N/4 = 256 blocks, block = 256 (thread = h), 4 rows per block.
// ---------------------------------------------------------------------------
__global__ __launch_bounds__(256) void k2_rows(
    const float* __restrict__ x, const float* __restrict__ W1,
    const float* __restrict__ ub, float* __restrict__ A,
    float* __restrict__ W) {
  __shared__ float xr[4][F];
  const int blk = blockIdx.x;
  const int b = blk >> 6;
  const int i0 = (blk & 63) * 4;
  const int t = threadIdx.x;  // h

  for (int idx = t; idx < 4 * F; idx += 256) {
    int r = idx >> 7, f = idx & (F - 1);
    xr[r][f] = fmaxf(x[(b * N + i0 + r) * F + f], 0.f);
  }
  __syncthreads();

  float aA[4], aW[4];
  const float u = ub[b * H + t];
#pragma unroll
  for (int r = 0; r < 4; ++r) { aA[r] = u; aW[r] = 0.f; }

  const float* W1i = W1 + F * H;
  const float* W1j = W1 + 2 * F * H;
#pragma unroll 4
  for (int f = 0; f < F; ++f) {
    const float wi = W1i[f * H + t];
    const float wj = W1j[f * H + t];
#pragma unroll
    for (int r = 0; r < 4; ++r) {
      const float xv = xr[r][f];
      aA[r] = fmaf(xv, wi, aA[r]);
      aW[r] = fmaf(xv, wj, aW[r]);
    }
  }
#pragma unroll
  for (int r = 0; r < 4; ++r) {
    A[(b * N + i0 + r) * H + t] = aA[r];
    W[(b * N + i0 + r) * H + t] = aW[r];
  }
}

// ---------------------------------------------------------------------------
// k3a: partial[c][b][i][j] = sum_{h in chunk c} relu(A[b,i,h]+W[b,j,h])*W2[h]
// 32x32 tile, 2x2 per thread, h split ACROSS blocks (2 chunks of 128).
// grid = (8, 8, B*2) = 512 blocks (2/CU, 8 waves/CU), block = 256.
// LDS ~35.3 KB. Transposed [h][row] stride 34 -> conflict-free float2 reads.
// ---------------------------------------------------------------------------
#define K3_STRIDE 34
__global__ __launch_bounds__(256) void k3a_pairwise(
    const float* __restrict__ A, const float* __restrict__ W,
    const float* __restrict__ W2, float* __restrict__ partial) {
  __shared__ float aT[128 * K3_STRIDE];
  __shared__ float wT[128 * K3_STRIDE];
  __shared__ float w2s[128];

  const int bz = blockIdx.z;
  const int b = bz >> 1;
  const int c = bz & 1;
  const int hbase = c * 128;
  const int i0 = blockIdx.y * 32;
  const int j0 = blockIdx.x * 32;
  const int t = threadIdx.x;
  const int tj = t & 15;
  const int ti = t >> 4;

  const float* Ab = A + (b * N + i0) * H + hbase;
  const float* Wb = W + (b * N + j0) * H + hbase;

  if (t < 128) w2s[t] = W2[hbase + t];

  const int hh = t & 127;  // h within chunk (coalesced across threads)
  const int rh = t >> 7;   // which 16 rows to stage
#pragma unroll
  for (int k = 0; k < 16; ++k) {
    const int r = rh * 16 + k;
    aT[hh * K3_STRIDE + r] = Ab[r * H + hh];
    wT[hh * K3_STRIDE + r] = Wb[r * H + hh];
  }
  __syncthreads();

  float acc00 = 0.f, acc01 = 0.f, acc10 = 0.f, acc11 = 0.f;
  const float* ap = aT + 2 * ti;
  const float* wp = wT + 2 * tj;
#pragma unroll 8
  for (int h = 0; h < 128; ++h) {
    const float2 av = *(const float2*)(ap + h * K3_STRIDE);
    const float2 wv = *(const float2*)(wp + h * K3_STRIDE);
    const float w2h = w2s[h];
    acc00 = fmaf(fmaxf(av.x + wv.x, 0.f), w2h, acc00);
    acc01 = fmaf(fmaxf(av.x + wv.y, 0.f), w2h, acc01);
    acc10 = fmaf(fmaxf(av.y + wv.x, 0.f), w2h, acc10);
    acc11 = fmaf(fmaxf(av.y + wv.y, 0.f), w2h, acc11);
  }

  float* P = partial + (size_t)c * (B * N * N);
  const int i = i0 + 2 * ti;
  const int j = j0 + 2 * tj;
  float* o0 = P + (b * N + i) * N + j;
  float* o1 = o0 + N;
  o0[0] = acc00;
  o0[1] = acc01;
  o1[0] = acc10;
  o1[1] = acc11;
}

// ---------------------------------------------------------------------------
// k3b: out = p0 + p1 + b2   (float4; 65536 float4 over 256 blocks x 256 thr)
// ---------------------------------------------------------------------------
__global__ __launch_bounds__(256) void k3b_reduce(
    const float* __restrict__ partial, const float* __restrict__ b2,
    float* __restrict__ out) {
  const int g = blockIdx.x * 256 + threadIdx.x;
  const float bb = b2[0];
  const float4 p0 = ((const float4*)partial)[g];
  const float4 p1 = ((const float4*)(partial + B * N * N))[g];
  float4 o;
  o.x = p0.x + p1.x + bb;
  o.y = p0.y + p1.y + bb;
  o.z = p0.z + p1.z + bb;
  o.w = p0.w + p1.w + bb;
  ((float4*)out)[g] = o;
}

extern "C" void kernel_launch(void* const* d_in, const int* in_sizes, int n_in,
                              void* d_out, int out_size, void* d_ws, size_t ws_size,
                              hipStream_t stream) {
  const float* x  = (const float*)d_in[0];  // [B,N,F]
  const float* Wp = (const float*)d_in[1];  // [F,F]
  const float* W1 = (const float*)d_in[2];  // [3F,H]
  const float* b1 = (const float*)d_in[3];  // [H]
  const float* W2 = (const float*)d_in[4];  // [H,1]
  const float* b2 = (const float*)d_in[5];  // [1]
  float* out = (float*)d_out;               // [B,N,N,1]

  float* ws = (float*)d_ws;
  float* ub      = ws;                       // B*H     = 1024
  float* A       = ub + B * H;               // B*N*H   = 262144
  float* Wt      = A + B * N * H;            // B*N*H   = 262144
  float* xm_acc  = Wt + B * N * H;           // B*F     = 512
  float* partial = xm_acc + B * F;           // 2*B*N*N = 524288
  // total: 1,050,112 floats = 4.2 MB of d_ws

  hipMemsetAsync(xm_acc, 0, B * F * sizeof(float), stream);
  k1a_mean<<<dim3(B * 16), dim3(256), 0, stream>>>(x, xm_acc);
  k1b_pooled<<<dim3(B * 2), dim3(256), 0, stream>>>(xm_acc, Wp, W1, b1, ub);
  k2_rows<<<dim3(B * N / 4), dim3(256), 0, stream>>>(x, W1, ub, A, Wt);
  k3a_pairwise<<<dim3(N / 32, N / 32, B * 2), dim3(256), 0, stream>>>(A, Wt, W2, partial);
  k3b_reduce<<<dim3(B * N * N / 4 / 256), dim3(256), 0, stream>>>(partial, b2, out);
}

// Round 3
// 89.129 us; speedup vs baseline: 1.4054x; 1.1146x over previous
//
#include <hip/hip_runtime.h>
#include <hip/hip_bf16.h>

// Problem constants (from reference):
#define B 4
#define N 256
#define F 128
#define H 256
// OUT = 1

// ---------------------------------------------------------------------------
// kAW: A[b,i,h] = relu(x[b,i,:]) @ W1[F:2F, :]      (NO ub term -- deferred)
//      W[b,j,h] = relu(x[b,j,:]) @ W1[2F:3F, :]
// grid = B*N/2 = 512 blocks (2 rows each), block = 256 (thread = h).
// Blocks 0..B-1 ALSO compute the pooled path for batch==blockIdx.x:
//      ub[b,h] = b1[h] + relu((mean_i x[b,i,:]) @ Wp) @ W1[0:F, :]
// (ub feeds only kPair, so no extra dispatch / dependency needed.)
// ---------------------------------------------------------------------------
__global__ __launch_bounds__(256) void kAW(
    const float* __restrict__ x, const float* __restrict__ Wp,
    const float* __restrict__ W1, const float* __restrict__ b1,
    float* __restrict__ ub, float* __restrict__ A, float* __restrict__ W) {
  __shared__ float xr[2][F];
  const int blk = blockIdx.x;
  const int b = blk >> 7;            // 128 blocks per batch
  const int i0 = (blk & 127) * 2;
  const int t = threadIdx.x;         // h

  // stage 2 relu'd input rows (256 floats -> one per thread)
  {
    const int r = t >> 7, f = t & 127;
    xr[r][f] = fmaxf(x[(b * N + i0 + r) * F + f], 0.f);
  }
  __syncthreads();

  float a0 = 0.f, a1 = 0.f, w0 = 0.f, w1 = 0.f;
  const float* W1i = W1 + F * H;       // rows F..2F-1
  const float* W1j = W1 + 2 * F * H;   // rows 2F..3F-1
#pragma unroll 8
  for (int f = 0; f < F; ++f) {
    const float wi = W1i[f * H + t];
    const float wj = W1j[f * H + t];
    const float x0 = xr[0][f];
    const float x1 = xr[1][f];
    a0 = fmaf(x0, wi, a0);
    a1 = fmaf(x1, wi, a1);
    w0 = fmaf(x0, wj, w0);
    w1 = fmaf(x1, wj, w1);
  }
  A[(b * N + i0) * H + t] = a0;
  A[(b * N + i0 + 1) * H + t] = a1;
  W[(b * N + i0) * H + t] = w0;
  W[(b * N + i0 + 1) * H + t] = w1;

  // ---- pooled path: 4 of 512 blocks, batch pb = blk (uniform branch) ----
  if (blk < B) {
    __shared__ float4 red4[256];
    __shared__ float xm_s[F];
    __shared__ float rp_s[F];
    __shared__ float part[256];
    const int pb = blk;
    const float4* xb4 = (const float4*)(x + pb * N * F);
    float4 acc = make_float4(0.f, 0.f, 0.f, 0.f);
#pragma unroll 8
    for (int k = 0; k < 32; ++k) {  // 8192 float4 total; col-group = t & 31
      const float4 v = xb4[t + 256 * k];
      acc.x += v.x; acc.y += v.y; acc.z += v.z; acc.w += v.w;
    }
    red4[t] = acc;
    __syncthreads();
    if (t < 32) {
      float4 s = red4[t];
#pragma unroll
      for (int m = 1; m < 8; ++m) {
        const float4 v = red4[t + 32 * m];
        s.x += v.x; s.y += v.y; s.z += v.z; s.w += v.w;
      }
      const float inv = 1.f / (float)N;
      xm_s[4 * t + 0] = s.x * inv;
      xm_s[4 * t + 1] = s.y * inv;
      xm_s[4 * t + 2] = s.z * inv;
      xm_s[4 * t + 3] = s.w * inv;
    }
    __syncthreads();
    // rp = relu(xm @ Wp): 2 threads per output, 64 MACs each
    {
      const int lo = t & 127, kh = t >> 7;
      float p = 0.f;
      const int k0 = kh * 64;
#pragma unroll 8
      for (int kk = 0; kk < 64; ++kk) {
        const int k = k0 + kk;
        p = fmaf(xm_s[k], Wp[k * F + lo], p);
      }
      part[t] = p;
    }
    __syncthreads();
    if (t < 128) rp_s[t] = fmaxf(part[t] + part[t + 128], 0.f);
    __syncthreads();
    // ub[pb, t] = b1[t] + rp @ W1[0:F, t]
    {
      float u = b1[t];
#pragma unroll 8
      for (int k = 0; k < F; ++k) u = fmaf(rp_s[k], W1[k * H + t], u);
      ub[pb * H + t] = u;
    }
  }
}

// ---------------------------------------------------------------------------
// kPair: out[b,i,j] = b2 + sum_h relu((A[b,i,h]+ub[b,h]) + W[b,j,h]) * W2[h]
// Tile 32i x 16j, FULL h=256 in-block (no partials, no reduce kernel).
// grid = (16 j-tiles, 8 i-tiles, B) = 512 blocks (2/CU, 8 waves/CU), blk=256.
// LDS: aT[256][34] (34.0 KB) + wT[256][17] (17.0 KB) + w2s (1 KB) ~ 53 KB.
// Writes 2-way bank aliased (free); reads are 8-way broadcasts (free).
// ---------------------------------------------------------------------------
#define SA 34
#define SW 17
__global__ __launch_bounds__(256) void kPair(
    const float* __restrict__ A, const float* __restrict__ W,
    const float* __restrict__ ub, const float* __restrict__ W2,
    const float* __restrict__ b2, float* __restrict__ out) {
  __shared__ float aT[256 * SA];  // [h][i-row 0..31]
  __shared__ float wT[256 * SW];  // [h][j-row 0..15]
  __shared__ float w2s[256];

  const int b = blockIdx.z;
  const int i0 = blockIdx.y * 32;
  const int j0 = blockIdx.x * 16;
  const int t = threadIdx.x;      // doubles as h during staging

  w2s[t] = W2[t];
  const float ubv = ub[b * H + t];  // ub for h = t, folded into aT staging

  const float* Ab = A + (b * N + i0) * H;
#pragma unroll 8
  for (int r = 0; r < 32; ++r)
    aT[t * SA + r] = Ab[r * H + t] + ubv;   // coalesced read, 2-way LDS write

  const float* Wb = W + (b * N + j0) * H;
#pragma unroll 8
  for (int r = 0; r < 16; ++r)
    wT[t * SW + r] = Wb[r * H + t];
  __syncthreads();

  const int ti = t >> 3;       // i-row 0..31
  const int tj = t & 7;        // j-pair 0..7
  float acc0 = 0.f, acc1 = 0.f;
#pragma unroll 8
  for (int h = 0; h < 256; ++h) {
    const float a  = aT[h * SA + ti];
    const float v0 = wT[h * SW + 2 * tj];
    const float v1 = wT[h * SW + 2 * tj + 1];
    const float w2 = w2s[h];
    acc0 = fmaf(fmaxf(a + v0, 0.f), w2, acc0);
    acc1 = fmaf(fmaxf(a + v1, 0.f), w2, acc1);
  }

  const float bb = b2[0];
  float* o = out + (b * N + i0 + ti) * N + j0 + 2 * tj;
  o[0] = acc0 + bb;
  o[1] = acc1 + bb;
}

extern "C" void kernel_launch(void* const* d_in, const int* in_sizes, int n_in,
                              void* d_out, int out_size, void* d_ws, size_t ws_size,
                              hipStream_t stream) {
  const float* x  = (const float*)d_in[0];  // [B,N,F]
  const float* Wp = (const float*)d_in[1];  // [F,F]
  const float* W1 = (const float*)d_in[2];  // [3F,H]
  const float* b1 = (const float*)d_in[3];  // [H]
  const float* W2 = (const float*)d_in[4];  // [H,1]
  const float* b2 = (const float*)d_in[5];  // [1]
  float* out = (float*)d_out;               // [B,N,N,1]

  float* ws = (float*)d_ws;
  float* ub = ws;                  // B*H   = 1024
  float* A  = ub + B * H;          // B*N*H = 262144
  float* W  = A + B * N * H;       // B*N*H = 262144
  // total: 525312 floats = 2.1 MB of d_ws; every element written before read

  kAW<<<dim3(B * N / 2), dim3(256), 0, stream>>>(x, Wp, W1, b1, ub, A, W);
  kPair<<<dim3(N / 16, N / 32, B), dim3(256), 0, stream>>>(A, W, ub, W2, b2, out);
}